// Round 8
// baseline (27541.064 us; speedup 1.0000x reference)
//
#include <hip/hip_runtime.h>
#include <hip/hip_cooperative_groups.h>

namespace cg = cooperative_groups;

// Problem dims
#define B_    128
#define H_    512
#define T_    512
#define FIN_  64
#define FOUT_ 8
#define WOUT_ 64
#define G4H_  2048   // 4*H_

// 64 blocks per layer (8 h-cols each = 32 gate rows), 512 threads (8 waves).
#define NBLK  192
#define NTHR  512
#define RD    4      // h ring depth (time-indexed, slot = idx % RD)

typedef __attribute__((ext_vector_type(8))) _Float16 half8;
typedef __attribute__((ext_vector_type(4))) float f32x4;
typedef unsigned short u16;
typedef unsigned int u32;

#define LOSCALE   4096.0f          // 2^12: lifts fp16 lo-plane out of subnormals
#define LOINV     0.000244140625f  // 2^-12

struct Params {
  const float *x, *eWih0, *eWih, *eWhh, *ebih, *ebhh;
  const float *dWih0, *dWih, *dWhh, *dbih, *dbhh, *fcw, *fcb;
  float *out; float *ws;
};

__device__ __forceinline__ float sigm(float x) { return 1.0f / (1.0f + __expf(-x)); }
__device__ __forceinline__ float tanhf_(float x) {
  float e = __expf(-2.0f * fabsf(x));
  return copysignf((1.0f - e) / (1.0f + e), x);
}
__device__ __forceinline__ u16 h2u(_Float16 h) {
  union { _Float16 f; u16 u; } v; v.f = h; return v.u;
}
__device__ __forceinline__ void split16(float w, u16& hi, u16& lo) {
  _Float16 h = (_Float16)w;
  _Float16 l = (_Float16)((w - (float)h) * LOSCALE);
  hi = h2u(h); lo = h2u(l);
}

// ---- flag sync: per-block slots, monotone step counters ----
// flags[g][64]: slot b = latest completed step of block b in group g.
// Signal: one release STORE to own slot (no RMW -> no serialization).
// Wait: waves 0..2 poll the 3 dependency groups' 64 slots in parallel.
__device__ __forceinline__ int aload(const int* p) {
  return __hip_atomic_load(p, __ATOMIC_RELAXED, __HIP_MEMORY_SCOPE_AGENT);
}
__device__ __forceinline__ void wait3(const int* a, int ta, const int* b, int tb,
                                      const int* c, int tc) {
  const int wv = threadIdx.x >> 6, s = threadIdx.x & 63;
  if (wv == 0 && a)      { while (aload(a + s) < ta) __builtin_amdgcn_s_sleep(2); }
  else if (wv == 1 && b) { while (aload(b + s) < tb) __builtin_amdgcn_s_sleep(2); }
  else if (wv == 2 && c) { while (aload(c + s) < tc) __builtin_amdgcn_s_sleep(2); }
  __syncthreads();
  if (threadIdx.x == 0) __threadfence();   // acquire: invalidate stale caches
  __syncthreads();
}
__device__ __forceinline__ void signal1(int* slot, int v) {
  __syncthreads();
  if (threadIdx.x == 0) {
    __threadfence();                       // release: write back dirty lines
    __hip_atomic_store(slot, v, __ATOMIC_RELAXED, __HIP_MEMORY_SCOPE_AGENT);
  }
}

// Stage this block's 32 gate rows of [Wi | Wh] into LDS as fp16 hi/lo planes,
// B-fragment order Wb[n][k], 16B-chunk XOR swizzle: chunk ^= n&15 (4-bit) so the
// 16 reader rows of an N-tile hit 16 distinct chunk offsets (no 2-way row clash).
__device__ void stage_w(u16* WbHi, u16* WbLo, const float* Wi, int Kreal, int K0pad,
                        const float* Wh, int j0) {
  const int rowlen = K0pad + H_;
  for (int n = 0; n < 32; ++n) {
    const int gr = (n >> 3) * H_ + j0 + (n & 7);
    const float* s0 = Wi + (size_t)gr * Kreal;
    const float* s1 = Wh + (size_t)gr * H_;
    const int swz = n & 15;
    for (int k = threadIdx.x; k < rowlen; k += NTHR) {
      float w = (k < K0pad) ? ((k < Kreal) ? s0[k] : 0.0f) : s1[k - K0pad];
      u16 hi, lo; split16(w, hi, lo);
      int kk = (k & 7) | ((((k >> 3) ^ swz)) << 3);
      WbHi[n * 1024 + kk] = hi;
      WbLo[n * 1024 + kk] = lo;
    }
  }
}

// One LSTM cell step. GEMM D[128 batch][32 gate-rows], fp16 split:
//   acc += Ah*Wh ; accL += Al*Wh + Ah*Wl ; D = acc + 2^-12 * accL.
// Wave tiling (r8): wave wv -> N-tile nt=wv>>2 (16 gate rows), M-pair mq=wv&3
// (batches mq*32..+31 as two 16-row M-tiles). B-reads halved vs r7; A-loads 4/chunk.
template <int NC0, bool DEC0, bool FC>
__device__ __forceinline__ void cell(
    const u16* __restrict__ WbHi, const u16* __restrict__ WbLo,
    float* __restrict__ gl, float* __restrict__ predl,
    const float* __restrict__ bias_s, const float* __restrict__ fcw_s,
    const u16* __restrict__ i0h, const u16* __restrict__ i0l, const int ld0,
    const float* __restrict__ pr_in,
    const u16* __restrict__ iHh, const u16* __restrict__ iHl,
    u16* __restrict__ ohh, u16* __restrict__ ohl, const int j0,
    float* __restrict__ creg, float* __restrict__ pr_out) {
  const int tid = threadIdx.x;
  const int lane = tid & 63, lr = lane & 15, lg = lane >> 4;
  const int wv = tid >> 6, nt = wv >> 2, mq = wv & 3;
  const int mb0 = mq * 32 + lr;            // A batch rows (two M-tiles)
  const int sw = lr;                       // 4-bit chunk XOR (matches stage_w n&15)

  f32x4 accA = {0.f,0.f,0.f,0.f}, accB = {0.f,0.f,0.f,0.f};
  f32x4 accAL = {0.f,0.f,0.f,0.f}, accBL = {0.f,0.f,0.f,0.f};

  const u16* bh = WbHi + (nt * 16 + lr) * 1024;
  const u16* bl = WbLo + (nt * 16 + lr) * 1024;
  constexpr int K0PAD = NC0 * 32;

#define MFMA6(AH0, AL0, AH1, AL1, CH)                                            \
  {                                                                              \
    half8 wh = *(const half8*)(bh + (((CH) ^ sw) << 3));                         \
    half8 wl = *(const half8*)(bl + (((CH) ^ sw) << 3));                         \
    accA  = __builtin_amdgcn_mfma_f32_16x16x32_f16(AH0, wh, accA, 0, 0, 0);      \
    accB  = __builtin_amdgcn_mfma_f32_16x16x32_f16(AH1, wh, accB, 0, 0, 0);      \
    accAL = __builtin_amdgcn_mfma_f32_16x16x32_f16(AL0, wh, accAL, 0, 0, 0);     \
    accBL = __builtin_amdgcn_mfma_f32_16x16x32_f16(AL1, wh, accBL, 0, 0, 0);     \
    accAL = __builtin_amdgcn_mfma_f32_16x16x32_f16(AH0, wl, accAL, 0, 0, 0);     \
    accBL = __builtin_amdgcn_mfma_f32_16x16x32_f16(AH1, wl, accBL, 0, 0, 0);     \
  }

  if constexpr (DEC0) {
    // in0 = pred feedback: fp32 [B][8], K padded to 32 (weight rows 8..31 = 0).
    half8 ah0 = {}, al0 = {}, ah1 = {}, al1 = {};
    if (lg == 0) {
      #pragma unroll
      for (int j = 0; j < 8; ++j) {
        float v0 = pr_in[mb0 * 8 + j], v1 = pr_in[(mb0 + 16) * 8 + j];
        _Float16 h0 = (_Float16)v0, h1 = (_Float16)v1;
        ah0[j] = h0; al0[j] = (_Float16)((v0 - (float)h0) * LOSCALE);
        ah1[j] = h1; al1[j] = (_Float16)((v1 - (float)h1) * LOSCALE);
      }
    }
    MFMA6(ah0, al0, ah1, al1, lg);
  } else {
    const u16* a0h = i0h + (size_t)mb0 * ld0 + lg * 8;
    const u16* a0l = i0l + (size_t)mb0 * ld0 + lg * 8;
    const int st = 16 * ld0;
    #pragma unroll
    for (int kk = 0; kk < NC0; ++kk) {
      half8 ah0 = *(const half8*)(a0h + kk * 32);
      half8 al0 = *(const half8*)(a0l + kk * 32);
      half8 ah1 = *(const half8*)(a0h + st + kk * 32);
      half8 al1 = *(const half8*)(a0l + st + kk * 32);
      MFMA6(ah0, al0, ah1, al1, kk * 4 + lg);
    }
  }
  {
    const u16* aHh = iHh + (size_t)mb0 * H_ + lg * 8;
    const u16* aHl = iHl + (size_t)mb0 * H_ + lg * 8;
    const int st = 16 * H_;
    #pragma unroll
    for (int kk = 0; kk < 16; ++kk) {
      half8 ah0 = *(const half8*)(aHh + kk * 32);
      half8 al0 = *(const half8*)(aHl + kk * 32);
      half8 ah1 = *(const half8*)(aHh + st + kk * 32);
      half8 al1 = *(const half8*)(aHl + st + kk * 32);
      MFMA6(ah0, al0, ah1, al1, K0PAD / 8 + kk * 4 + lg);
    }
  }
#undef MFMA6

  // fold lo-plane accumulators (carry 2^12)
  #pragma unroll
  for (int i = 0; i < 4; ++i) {
    accA[i] = fmaf(accAL[i], LOINV, accA[i]);
    accB[i] = fmaf(accBL[i], LOINV, accB[i]);
  }

  // gates -> LDS: row = gate row, 16B m-chunks XOR'd by row&7.
  // accA covers m = mq*32 + lg*4 + r (chunk mq*8+lg); accB m += 16 (chunk +4).
  const int row = nt * 16 + lr, rsw = row & 7;
  *(f32x4*)(gl + row * 128 + (((mq * 8 + lg) ^ rsw) << 2)) = accA;
  *(f32x4*)(gl + row * 128 + (((mq * 8 + 4 + lg) ^ rsw) << 2)) = accB;
  __syncthreads();

  // elementwise: thread owns (batch b, cols c0..c0+1)
  const int b = tid & 127, c0 = (tid >> 7) << 1;
  float hv[2];
  #pragma unroll
  for (int u = 0; u < 2; ++u) {
    const int cc = c0 + u;
    const int bs = b >> 2, bo = b & 3;
    float gi = gl[(cc) * 128 + ((bs ^ (cc & 7)) << 2) + bo] + bias_s[cc];
    float gf = gl[(8 + cc) * 128 + ((bs ^ ((8 + cc) & 7)) << 2) + bo] + bias_s[8 + cc];
    float gg = gl[(16 + cc) * 128 + ((bs ^ ((16 + cc) & 7)) << 2) + bo] + bias_s[16 + cc];
    float go = gl[(24 + cc) * 128 + ((bs ^ ((24 + cc) & 7)) << 2) + bo] + bias_s[24 + cc];
    float cv = sigm(gf) * creg[u] + sigm(gi) * tanhf_(gg);
    creg[u] = cv;
    hv[u] = sigm(go) * tanhf_(cv);
  }
  u16 h0b, l0b, h1b, l1b;
  split16(hv[0], h0b, l0b);
  split16(hv[1], h1b, l1b);
  *(u32*)(ohh + (size_t)b * H_ + j0 + c0) = (u32)h0b | ((u32)h1b << 16);
  *(u32*)(ohl + (size_t)b * H_ + j0 + c0) = (u32)l0b | ((u32)l1b << 16);

  if constexpr (FC) {
    for (int i = tid; i < FOUT_ * B_; i += NTHR) predl[i] = 0.0f;
    __syncthreads();
    #pragma unroll
    for (int f = 0; f < 8; ++f)
      atomicAdd(&predl[b * 8 + f],
                hv[0] * fcw_s[f * 8 + c0] + hv[1] * fcw_s[f * 8 + c0 + 1]);
    __syncthreads();
    for (int i = tid; i < FOUT_ * B_; i += NTHR) atomicAdd(&pr_out[i], predl[i]);
  }
}

__global__ void __launch_bounds__(NTHR, 1) lstm_all(Params p) {
  __shared__ __align__(16) u16 WbHi[32 * 1024];
  __shared__ __align__(16) u16 WbLo[32 * 1024];
  __shared__ __align__(16) float gl[32 * B_];
  __shared__ float predl[FOUT_ * B_];
  __shared__ float bias_s[32];
  __shared__ float fcw_s[64];

  const int tid = threadIdx.x;
  const int bid = blockIdx.x;
  const int layer = bid >> 6;
  const int blk = bid & 63;
  const int j0 = blk * 8;
  const size_t HB = (size_t)B_ * H_;

  // ws layout (~23.4MB):
  u16* xb = (u16*)p.ws;                               // [2][T][B][FIN] fp16 planes
  u16* ehb = xb + (size_t)2 * T_ * B_ * FIN_;         // enc ring [3][RD][2][B][H]
  u16* dhb = ehb + (size_t)3 * RD * 2 * HB;           // dec ring [3][RD][2][B][H]
  float* pr = (float*)(dhb + (size_t)3 * RD * 2 * HB);  // [65][B][8] fp32
  int* f_enc = (int*)(pr + (size_t)65 * B_ * FOUT_);  // [3][64] per-block step count
  int* f_dec = f_enc + 3 * 64;                        // [3][64], -1 until enc->dec copy

  cg::grid_group grid = cg::this_grid();
  const int gid = bid * NTHR + tid, gstep = NBLK * NTHR;

  // ---- init ----
  for (int i = gid; i < 3 * 65536; i += gstep) {      // zero enc ring slot 0
    int l = i >> 16, off = i & 65535;
    ((u32*)ehb)[(size_t)l * (RD * 65536) + off] = 0u;
  }
  for (int i = gid; i < 3 * 64; i += gstep) { f_enc[i] = 0; f_dec[i] = -1; }
  for (int i = gid; i < 65 * B_ * FOUT_; i += gstep) {
    int d = i >> 10, r = i & 1023, b = r >> 3, f = r & 7;
    // pred[0] = dec_in = x[:, -1, :FOUT] (last feature, times 0..7); rest = fc bias.
    pr[i] = (d == 0) ? p.x[((size_t)b * FIN_ + (FIN_ - 1)) * T_ + f] : p.fcb[f];
  }
  {
    const size_t XE0 = (size_t)T_ * B_ * FIN_;
    for (int i = gid; i < T_ * B_ * FIN_; i += gstep) {
      int t = i & 511, f = (i >> 9) & 63, b = i >> 15;
      float v = p.x[((size_t)b * FIN_ + f) * T_ + t];
      u16 hi, lo; split16(v, hi, lo);
      size_t o = ((size_t)t * B_ + b) * FIN_ + f;
      xb[o] = hi;
      xb[XE0 + o] = lo;
    }
  }
  if (layer == 0)      stage_w(WbHi, WbLo, p.eWih0, FIN_, FIN_, p.eWhh, j0);
  else if (layer == 1) stage_w(WbHi, WbLo, p.eWih, H_, H_, p.eWhh + (size_t)G4H_ * H_, j0);
  else                 stage_w(WbHi, WbLo, p.eWih + (size_t)G4H_ * H_, H_, H_,
                               p.eWhh + (size_t)2 * G4H_ * H_, j0);
  if (tid < 32) {
    int gr = (tid >> 3) * H_ + j0 + (tid & 7);
    bias_s[tid] = p.ebih[layer * G4H_ + gr] + p.ebhh[layer * G4H_ + gr];
  }
  grid.sync();   // the ONLY grid-wide barrier

  float creg[2] = {0.0f, 0.0f};
  const size_t XE = (size_t)T_ * B_ * FIN_;
  auto ep = [&](int l, int idx, int pl) -> u16* {
    return ehb + (((size_t)l * RD + (idx & (RD - 1))) * 2 + pl) * HB;
  };
  auto dp = [&](int l, int idx, int pl) -> u16* {
    return dhb + (((size_t)l * RD + (idx & (RD - 1))) * 2 + pl) * HB;
  };

  // ---- Encoder dataflow (flag value = completed steps). Step t:
  // sib f_enc[l] >= t, producer f_enc[l-1] >= t+1, BP f_enc[l+1] >= t-(RD-1).
  for (int t = 0; t < T_; ++t) {
    wait3(f_enc + layer * 64, t,
          (layer > 0) ? f_enc + (layer - 1) * 64 : nullptr, t + 1,
          (layer < 2 && t >= RD) ? f_enc + (layer + 1) * 64 : nullptr, t - (RD - 1));
    if (layer == 0) {
      cell<2, false, false>(WbHi, WbLo, gl, predl, bias_s, fcw_s,
                            xb + (size_t)t * B_ * FIN_, xb + XE + (size_t)t * B_ * FIN_,
                            FIN_, nullptr,
                            ep(0, t, 0), ep(0, t, 1),
                            ep(0, t + 1, 0), ep(0, t + 1, 1), j0, creg, nullptr);
    } else {
      cell<16, false, false>(WbHi, WbLo, gl, predl, bias_s, fcw_s,
                             ep(layer - 1, t + 1, 0), ep(layer - 1, t + 1, 1), H_, nullptr,
                             ep(layer, t, 0), ep(layer, t, 1),
                             ep(layer, t + 1, 0), ep(layer, t + 1, 1), j0, creg, nullptr);
    }
    if (t == T_ - 1) {
      __syncthreads();   // own block's h writes visible block-wide
      const u32* src = (const u32*)ep(layer, T_, 0);
      u32* dst = (u32*)dp(layer, 0, 0);
      for (int i = tid; i < 1024; i += NTHR) {
        int pl = i >> 9, b = (i >> 2) & 127, w = i & 3;
        size_t o = (size_t)pl * (HB >> 1) + (size_t)b * (H_ >> 1) + (j0 >> 1) + w;
        dst[o] = src[o];
      }
      __syncthreads();
      if (tid == 0) {
        __threadfence();
        __hip_atomic_store(&f_dec[layer * 64 + blk], 0, __ATOMIC_RELAXED,
                           __HIP_MEMORY_SCOPE_AGENT);
        __hip_atomic_store(&f_enc[layer * 64 + blk], T_, __ATOMIC_RELAXED,
                           __HIP_MEMORY_SCOPE_AGENT);
      }
    } else {
      signal1(&f_enc[layer * 64 + blk], t + 1);
    }
  }

  // ---- restage decoder weights/bias/fcw (block-local; signal1 synced above) ----
  if (layer == 0)      stage_w(WbHi, WbLo, p.dWih0, FOUT_, 32, p.dWhh, j0);
  else if (layer == 1) stage_w(WbHi, WbLo, p.dWih, H_, H_, p.dWhh + (size_t)G4H_ * H_, j0);
  else                 stage_w(WbHi, WbLo, p.dWih + (size_t)G4H_ * H_, H_, H_,
                               p.dWhh + (size_t)2 * G4H_ * H_, j0);
  if (tid < 32) {
    int gr = (tid >> 3) * H_ + j0 + (tid & 7);
    bias_s[tid] = p.dbih[layer * G4H_ + gr] + p.dbhh[layer * G4H_ + gr];
  }
  if (layer == 2 && tid < 64)
    fcw_s[tid] = p.fcw[(size_t)(tid >> 3) * H_ + j0 + (tid & 7)];

  // ---- Decoder: flag value = completed steps (0 = enc->dec copy done).
  for (int d = 0; d < WOUT_; ++d) {
    if (layer == 0) {
      wait3(f_dec + 0 * 64, d,                                  // sib (d=0: copy)
            (d > 0) ? f_dec + 2 * 64 : nullptr, d,              // pred[d] via L2
            (d >= RD) ? f_dec + 1 * 64 : nullptr, d - (RD - 1));  // ring BP
      cell<1, true, false>(WbHi, WbLo, gl, predl, bias_s, fcw_s,
                           nullptr, nullptr, 0, pr + (size_t)d * B_ * FOUT_,
                           dp(0, d, 0), dp(0, d, 1),
                           dp(0, d + 1, 0), dp(0, d + 1, 1), j0, creg, nullptr);
      signal1(&f_dec[0 * 64 + blk], d + 1);
    } else if (layer == 1) {
      wait3(f_dec + 1 * 64, d,
            f_dec + 0 * 64, d + 1,
            (d >= RD) ? f_dec + 2 * 64 : nullptr, d - (RD - 1));
      cell<16, false, false>(WbHi, WbLo, gl, predl, bias_s, fcw_s,
                             dp(0, d + 1, 0), dp(0, d + 1, 1), H_, nullptr,
                             dp(1, d, 0), dp(1, d, 1),
                             dp(1, d + 1, 0), dp(1, d + 1, 1), j0, creg, nullptr);
      signal1(&f_dec[1 * 64 + blk], d + 1);
    } else {
      wait3(f_dec + 2 * 64, d, f_dec + 1 * 64, d + 1, nullptr, 0);
      cell<16, false, true>(WbHi, WbLo, gl, predl, bias_s, fcw_s,
                            dp(1, d + 1, 0), dp(1, d + 1, 1), H_, nullptr,
                            dp(2, d, 0), dp(2, d, 1),
                            dp(2, d + 1, 0), dp(2, d + 1, 1), j0, creg,
                            pr + (size_t)(d + 1) * B_ * FOUT_);
      signal1(&f_dec[2 * 64 + blk], d + 1);   // covers pred[d+1] too
    }
  }

  // ---- outputs: L0 block k writes out[:, :, k] from pred idx k+1.
  // k<63: acquired at step k+1's wait; k==63 waits explicitly.
  if (layer == 0) {
    const int k = bid;
    if (k == WOUT_ - 1) wait3(f_dec + 2 * 64, WOUT_, nullptr, 0, nullptr, 0);
    const float* s = pr + (size_t)(k + 1) * B_ * FOUT_;
    for (int i = tid; i < B_ * FOUT_; i += NTHR) {
      int b = i >> 3, f = i & 7;
      p.out[((size_t)b * FOUT_ + f) * WOUT_ + k] = s[i];
    }
  }
}

extern "C" void kernel_launch(void* const* d_in, const int* in_sizes, int n_in,
                              void* d_out, int out_size, void* d_ws, size_t ws_size,
                              hipStream_t stream) {
  (void)in_sizes; (void)n_in; (void)out_size; (void)ws_size;
  Params p;
  p.x     = (const float*)d_in[0];
  p.eWih0 = (const float*)d_in[1];
  p.eWih  = (const float*)d_in[2];
  p.eWhh  = (const float*)d_in[3];
  p.ebih  = (const float*)d_in[4];
  p.ebhh  = (const float*)d_in[5];
  p.dWih0 = (const float*)d_in[6];
  p.dWih  = (const float*)d_in[7];
  p.dWhh  = (const float*)d_in[8];
  p.dbih  = (const float*)d_in[9];
  p.dbhh  = (const float*)d_in[10];
  p.fcw   = (const float*)d_in[11];
  p.fcb   = (const float*)d_in[12];
  p.out   = (float*)d_out;
  p.ws    = (float*)d_ws;
  void* args[] = { &p };
  hipLaunchCooperativeKernel((const void*)lstm_all, dim3(NBLK), dim3(NTHR), args, 0,
                             stream);
}